// Round 1
// baseline (8130.676 us; speedup 1.0000x reference)
//
#include <hip/hip_runtime.h>

typedef unsigned short u16;
typedef unsigned int u32;
typedef __attribute__((ext_vector_type(8))) short short8;
typedef __attribute__((ext_vector_type(4))) float floatx4;

#define Bc 4
#define Tc 1024
#define Dc 1024
#define Hc 16
#define Lc 8
#define Vc 50257
#define VPAD 50304   // V padded to multiple of 128 for tile staging

__device__ __forceinline__ float b2f(u16 u) {
    union { u32 i; float f; } x; x.i = ((u32)u) << 16; return x.f;
}
__device__ __forceinline__ u16 f2b(float f) {
    u32 u = __float_as_uint(f);
    u += 0x7FFFu + ((u >> 16) & 1u);   // RNE
    return (u16)(u >> 16);
}

// ---------------------------------------------------------------------------
// Embedding: x[b,t,:] = tok_emb[idx[b,t],:] + pos_emb[t,:]   (fp32)
// ---------------------------------------------------------------------------
__global__ __launch_bounds__(256) void embed_kernel(
    const int* __restrict__ idx, const float* __restrict__ tok,
    const float* __restrict__ pos, float* __restrict__ x)
{
    const int bt = blockIdx.x;
    const int tpos = bt & (Tc - 1);
    const int id = idx[bt];
    const int t = threadIdx.x;
    float4 tv = reinterpret_cast<const float4*>(tok + (size_t)id * Dc)[t];
    float4 pv = reinterpret_cast<const float4*>(pos + (size_t)tpos * Dc)[t];
    float4 r;
    r.x = tv.x + pv.x; r.y = tv.y + pv.y; r.z = tv.z + pv.z; r.w = tv.w + pv.w;
    reinterpret_cast<float4*>(x + (size_t)bt * Dc)[t] = r;
}

// ---------------------------------------------------------------------------
// fp32 -> bf16 elementwise (for tok_emb; tok_emb is already [N][K]=[V][D])
// ---------------------------------------------------------------------------
__global__ __launch_bounds__(256) void cvt_kernel(
    const float* __restrict__ in, u16* __restrict__ out, long n4)
{
    long i = (long)blockIdx.x * 256 + threadIdx.x;
    if (i >= n4) return;
    float4 v = reinterpret_cast<const float4*>(in)[i];
    short4 o;
    o.x = (short)f2b(v.x); o.y = (short)f2b(v.y);
    o.z = (short)f2b(v.z); o.w = (short)f2b(v.w);
    reinterpret_cast<short4*>(out)[i] = o;
}

// ---------------------------------------------------------------------------
// fp32 [K][N] -> bf16 [N][K] transpose-convert (weights -> B^T layout)
// ---------------------------------------------------------------------------
__global__ __launch_bounds__(256) void cvtT_kernel(
    const float* __restrict__ in, u16* __restrict__ out, int K, int N)
{
    __shared__ u16 tile[32][33];
    const int n0 = blockIdx.x * 32, k0 = blockIdx.y * 32;
    const int tx = threadIdx.x & 31, ty = threadIdx.x >> 5;  // ty 0..7
#pragma unroll
    for (int i = 0; i < 32; i += 8)
        tile[ty + i][tx] = f2b(in[(size_t)(k0 + ty + i) * N + n0 + tx]);
    __syncthreads();
#pragma unroll
    for (int i = 0; i < 32; i += 8)
        out[(size_t)(n0 + ty + i) * K + k0 + tx] = tile[tx][ty + i];
}

// ---------------------------------------------------------------------------
// LayerNorm (fp32 in, bf16 out): one block per row, D=1024
// ---------------------------------------------------------------------------
__global__ __launch_bounds__(256) void ln_kernel(
    const float* __restrict__ x, const float* __restrict__ sc,
    const float* __restrict__ bi, u16* __restrict__ out)
{
    const int row = blockIdx.x;
    const int t = threadIdx.x;
    const float4 v = reinterpret_cast<const float4*>(x + (size_t)row * Dc)[t];
    float s = v.x + v.y + v.z + v.w;
    float q = v.x * v.x + v.y * v.y + v.z * v.z + v.w * v.w;
#pragma unroll
    for (int off = 32; off > 0; off >>= 1) {
        s += __shfl_down(s, off);
        q += __shfl_down(q, off);
    }
    __shared__ float st[10];
    const int wave = t >> 6, lane = t & 63;
    if (lane == 0) { st[wave] = s; st[4 + wave] = q; }
    __syncthreads();
    if (t == 0) {
        float S = st[0] + st[1] + st[2] + st[3];
        float Q = st[4] + st[5] + st[6] + st[7];
        float m = S * (1.f / Dc);
        float var = Q * (1.f / Dc) - m * m;
        st[8] = m;
        st[9] = rsqrtf(var + 1e-5f);
    }
    __syncthreads();
    const float m = st[8], inv = st[9];
    const float4 sv = reinterpret_cast<const float4*>(sc)[t];
    const float4 bv = reinterpret_cast<const float4*>(bi)[t];
    short4 o;
    o.x = (short)f2b((v.x - m) * inv * sv.x + bv.x);
    o.y = (short)f2b((v.y - m) * inv * sv.y + bv.y);
    o.z = (short)f2b((v.z - m) * inv * sv.z + bv.z);
    o.w = (short)f2b((v.w - m) * inv * sv.w + bv.w);
    reinterpret_cast<short4*>(out + (size_t)row * Dc)[t] = o;
}

// ---------------------------------------------------------------------------
// GEMM: C[M,N] = f(A[M,K] @ Bt[N,K]^T + bias)
// bf16 A, bf16 Bt (both K-contiguous), fp32 accumulate via MFMA 16x16x32.
// Tile 128x128x32, 256 threads = 4 waves, each wave 64x64 (4x4 MFMA tiles).
// OUT_MODE: 0 = bf16 store; 1 = fp32 "+=" (residual add); 2 = fp32 store with
// col < N guard (logits, N not a multiple of 128; Bt rows padded to VPAD).
// ---------------------------------------------------------------------------
template <int OUT_MODE, bool HAS_BIAS, bool DO_GELU>
__global__ __launch_bounds__(256) void gemm_bt(
    const u16* __restrict__ A, const u16* __restrict__ Bt,
    const float* __restrict__ bias, void* __restrict__ C,
    int N, int K, int ldc)
{
    __shared__ __align__(16) u16 As[128 * 32];
    __shared__ __align__(16) u16 Bs[128 * 32];
    const int tid = threadIdx.x;
    const int m0 = blockIdx.y * 128;
    const int n0 = blockIdx.x * 128;
    const int wave = tid >> 6;
    const int lane = tid & 63;
    const int quad = lane >> 4;
    const int l16 = lane & 15;
    const int wr = (wave >> 1) * 64;
    const int wc = (wave & 1) * 64;

    floatx4 acc[4][4];
#pragma unroll
    for (int i = 0; i < 4; ++i)
#pragma unroll
        for (int j = 0; j < 4; ++j) {
            floatx4 z = {0.f, 0.f, 0.f, 0.f};
            acc[i][j] = z;
        }

    const int r0 = tid >> 2;            // 0..63
    const int cc0 = (tid & 3) * 8;      // 0,8,16,24

    for (int k0 = 0; k0 < K; k0 += 32) {
        uint4 a0 = *reinterpret_cast<const uint4*>(A + (size_t)(m0 + r0) * K + k0 + cc0);
        uint4 a1 = *reinterpret_cast<const uint4*>(A + (size_t)(m0 + r0 + 64) * K + k0 + cc0);
        uint4 b0 = *reinterpret_cast<const uint4*>(Bt + (size_t)(n0 + r0) * K + k0 + cc0);
        uint4 b1 = *reinterpret_cast<const uint4*>(Bt + (size_t)(n0 + r0 + 64) * K + k0 + cc0);
        *reinterpret_cast<uint4*>(&As[r0 * 32 + cc0]) = a0;
        *reinterpret_cast<uint4*>(&As[(r0 + 64) * 32 + cc0]) = a1;
        *reinterpret_cast<uint4*>(&Bs[r0 * 32 + cc0]) = b0;
        *reinterpret_cast<uint4*>(&Bs[(r0 + 64) * 32 + cc0]) = b1;
        __syncthreads();

        short8 af[4], bfr[4];
#pragma unroll
        for (int i = 0; i < 4; ++i)
            af[i] = *reinterpret_cast<const short8*>(&As[(wr + i * 16 + l16) * 32 + quad * 8]);
#pragma unroll
        for (int j = 0; j < 4; ++j)
            bfr[j] = *reinterpret_cast<const short8*>(&Bs[(wc + j * 16 + l16) * 32 + quad * 8]);
#pragma unroll
        for (int i = 0; i < 4; ++i)
#pragma unroll
            for (int j = 0; j < 4; ++j)
                acc[i][j] = __builtin_amdgcn_mfma_f32_16x16x32_bf16(af[i], bfr[j], acc[i][j], 0, 0, 0);
        __syncthreads();
    }

#pragma unroll
    for (int j = 0; j < 4; ++j) {
        const int col = n0 + wc + j * 16 + l16;
        float bv = 0.f;
        if (HAS_BIAS) bv = bias[col];
#pragma unroll
        for (int i = 0; i < 4; ++i) {
            const int rowb = m0 + wr + i * 16 + quad * 4;
#pragma unroll
            for (int r = 0; r < 4; ++r) {
                float v = acc[i][j][r] + bv;
                if (DO_GELU) v = 0.5f * v * (1.f + erff(v * 0.70710678118f));
                const size_t off = (size_t)(rowb + r) * ldc + col;
                if (OUT_MODE == 0) {
                    ((u16*)C)[off] = f2b(v);
                } else if (OUT_MODE == 1) {
                    ((float*)C)[off] += v;
                } else {
                    if (col < N) ((float*)C)[off] = v;
                }
            }
        }
    }
}

// ---------------------------------------------------------------------------
// Attention (VALU round-0): one WG = (b, h, 8 q-rows). Scores+softmax in LDS.
// qkv layout: [B*T][3072], q at +0, k at +1024, v at +2048, head h at h*64.
// ---------------------------------------------------------------------------
__global__ __launch_bounds__(256) void attn_kernel(
    const u16* __restrict__ qkv, u16* __restrict__ o)
{
    const int qt = blockIdx.x;
    const int h = blockIdx.y;
    const int b = blockIdx.z;
    const int q0 = qt * 8;
    const int klen = q0 + 8;
    __shared__ float sc[Tc][8];     // 32 KB, layout [k][qi]
    __shared__ float po[4][8][64];  // 8 KB partial O
    __shared__ float red[8][32];
    __shared__ float rowstat[16];   // [0..7]=max, [8..15]=1/sum
    const int tid = threadIdx.x;

    // ---- scores: thread (qi = tid&7, ks = tid>>3) ----
    {
        const int qi = tid & 7;
        const int ks = tid >> 3;
        float qreg[64];
        const u16* qrow = qkv + ((size_t)(b * Tc + q0 + qi)) * 3072 + h * 64;
#pragma unroll
        for (int c = 0; c < 8; ++c) {
            short8 qv = *reinterpret_cast<const short8*>(qrow + c * 8);
#pragma unroll
            for (int j2 = 0; j2 < 8; ++j2)
                qreg[c * 8 + j2] = b2f((u16)qv[j2]) * 0.125f;  // fold 1/sqrt(64)
        }
        for (int k = ks; k < klen; k += 32) {
            const u16* krow = qkv + ((size_t)(b * Tc + k)) * 3072 + 1024 + h * 64;
            float s = 0.f;
#pragma unroll
            for (int c = 0; c < 8; ++c) {
                short8 kv = *reinterpret_cast<const short8*>(krow + c * 8);
#pragma unroll
                for (int j2 = 0; j2 < 8; ++j2)
                    s += qreg[c * 8 + j2] * b2f((u16)kv[j2]);
            }
            sc[k][qi] = (k <= q0 + qi) ? s : -1e30f;
        }
    }
    __syncthreads();

    // ---- softmax over k for each of 8 rows ----
    {
        const int r = tid >> 5, j = tid & 31;
        float mx = -1e30f;
        for (int k = j; k < klen; k += 32) mx = fmaxf(mx, sc[k][r]);
        red[r][j] = mx;
        __syncthreads();
        if (tid < 8) {
            float m = red[tid][0];
            for (int i = 1; i < 32; ++i) m = fmaxf(m, red[tid][i]);
            rowstat[tid] = m;
        }
        __syncthreads();
        const float m = rowstat[r];
        float ssum = 0.f;
        for (int k = j; k < klen; k += 32) {
            float p = __expf(sc[k][r] - m);
            sc[k][r] = p;
            ssum += p;
        }
        red[r][j] = ssum;
        __syncthreads();
        if (tid < 8) {
            float s2 = 0.f;
            for (int i = 0; i < 32; ++i) s2 += red[tid][i];
            rowstat[8 + tid] = 1.f / s2;
        }
    }
    __syncthreads();

    // ---- PV: thread (d = tid&63, g = tid>>6), k strided by 4 groups ----
    {
        const int d = tid & 63, g = tid >> 6;
        float oa[8] = {0.f, 0.f, 0.f, 0.f, 0.f, 0.f, 0.f, 0.f};
        for (int k = g; k < klen; k += 4) {
            float v = b2f(qkv[((size_t)(b * Tc + k)) * 3072 + 2048 + h * 64 + d]);
            const float4 p0 = *reinterpret_cast<const float4*>(&sc[k][0]);
            const float4 p1 = *reinterpret_cast<const float4*>(&sc[k][4]);
            oa[0] += p0.x * v; oa[1] += p0.y * v; oa[2] += p0.z * v; oa[3] += p0.w * v;
            oa[4] += p1.x * v; oa[5] += p1.y * v; oa[6] += p1.z * v; oa[7] += p1.w * v;
        }
#pragma unroll
        for (int qi = 0; qi < 8; ++qi) po[g][qi][d] = oa[qi];
    }
    __syncthreads();
    for (int e = tid; e < 512; e += 256) {
        const int qi = e >> 6, dd = e & 63;
        float v = (po[0][qi][dd] + po[1][qi][dd] + po[2][qi][dd] + po[3][qi][dd]) *
                  rowstat[8 + qi];
        o[((size_t)(b * Tc + q0 + qi)) * Dc + h * 64 + dd] = f2b(v);
    }
}

// ---------------------------------------------------------------------------
extern "C" void kernel_launch(void* const* d_in, const int* in_sizes, int n_in,
                              void* d_out, int out_size, void* d_ws, size_t ws_size,
                              hipStream_t stream)
{
    const int*   idx    = (const int*)d_in[0];
    const float* tok    = (const float*)d_in[1];
    const float* pos    = (const float*)d_in[2];
    const float* qkv_w  = (const float*)d_in[3];
    const float* qkv_b  = (const float*)d_in[4];
    const float* proj_w = (const float*)d_in[5];
    const float* proj_b = (const float*)d_in[6];
    const float* ff1_w  = (const float*)d_in[7];
    const float* ff1_b  = (const float*)d_in[8];
    const float* ff2_w  = (const float*)d_in[9];
    const float* ff2_b  = (const float*)d_in[10];
    const float* ln1_s  = (const float*)d_in[11];
    const float* ln1_b  = (const float*)d_in[12];
    const float* ln2_s  = (const float*)d_in[13];
    const float* ln2_b  = (const float*)d_in[14];
    const float* lnf_s  = (const float*)d_in[15];
    const float* lnf_b  = (const float*)d_in[16];

    char* ws = (char*)d_ws;
    size_t off = 0;
    auto alloc = [&](size_t bytes) -> void* {
        void* p = ws + off;
        off += (bytes + 255) & ~(size_t)255;
        return p;
    };
    float* xres = (float*)alloc((size_t)4096 * 1024 * 4);   // fp32 residual
    u16* hbuf   = (u16*)alloc((size_t)4096 * 1024 * 2);     // LN out (bf16)
    u16* qkvb   = (u16*)alloc((size_t)4096 * 3072 * 2);
    u16* ob     = (u16*)alloc((size_t)4096 * 1024 * 2);
    u16* ffh    = (u16*)alloc((size_t)4096 * 4096 * 2);
    u16* wqT    = (u16*)alloc((size_t)3072 * 1024 * 2);
    u16* wpT    = (u16*)alloc((size_t)1024 * 1024 * 2);
    u16* wf1T   = (u16*)alloc((size_t)4096 * 1024 * 2);
    u16* wf2T   = (u16*)alloc((size_t)1024 * 4096 * 2);
    u16* temb   = (u16*)alloc((size_t)VPAD * 1024 * 2);
    // total ~210 MB

    embed_kernel<<<dim3(Bc * Tc), dim3(256), 0, stream>>>(idx, tok, pos, xres);
    const long n4 = (long)Vc * Dc / 4;
    cvt_kernel<<<dim3((unsigned)((n4 + 255) / 256)), dim3(256), 0, stream>>>(tok, temb, n4);

    for (int l = 0; l < Lc; ++l) {
        cvtT_kernel<<<dim3(3072 / 32, 1024 / 32), 256, 0, stream>>>(
            qkv_w + (size_t)l * 1024 * 3072, wqT, 1024, 3072);
        cvtT_kernel<<<dim3(1024 / 32, 1024 / 32), 256, 0, stream>>>(
            proj_w + (size_t)l * 1024 * 1024, wpT, 1024, 1024);
        cvtT_kernel<<<dim3(4096 / 32, 1024 / 32), 256, 0, stream>>>(
            ff1_w + (size_t)l * 1024 * 4096, wf1T, 1024, 4096);
        cvtT_kernel<<<dim3(1024 / 32, 4096 / 32), 256, 0, stream>>>(
            ff2_w + (size_t)l * 4096 * 1024, wf2T, 4096, 1024);

        ln_kernel<<<4096, 256, 0, stream>>>(xres, ln1_s + l * 1024, ln1_b + l * 1024, hbuf);
        gemm_bt<0, true, false><<<dim3(3072 / 128, 4096 / 128), 256, 0, stream>>>(
            hbuf, wqT, qkv_b + l * 3072, qkvb, 3072, 1024, 3072);
        attn_kernel<<<dim3(Tc / 8, Hc, Bc), 256, 0, stream>>>(qkvb, ob);
        gemm_bt<1, true, false><<<dim3(1024 / 128, 4096 / 128), 256, 0, stream>>>(
            ob, wpT, proj_b + l * 1024, xres, 1024, 1024, 1024);
        ln_kernel<<<4096, 256, 0, stream>>>(xres, ln2_s + l * 1024, ln2_b + l * 1024, hbuf);
        gemm_bt<0, true, true><<<dim3(4096 / 128, 4096 / 128), 256, 0, stream>>>(
            hbuf, wf1T, ff1_b + l * 4096, ffh, 4096, 1024, 4096);
        gemm_bt<1, true, false><<<dim3(1024 / 128, 4096 / 128), 256, 0, stream>>>(
            ffh, wf2T, ff2_b + l * 1024, xres, 1024, 4096, 1024);
    }

    ln_kernel<<<4096, 256, 0, stream>>>(xres, lnf_s, lnf_b, hbuf);
    gemm_bt<2, false, false><<<dim3((Vc + 127) / 128, 4096 / 128), 256, 0, stream>>>(
        hbuf, temb, nullptr, d_out, Vc, 1024, Vc);
}